// Round 13
// baseline (278.637 us; speedup 1.0000x reference)
//
#include <hip/hip_runtime.h>

#define BB 16
#define NN 8192
#define DMODEL 256
#define DKK 64
#define DVV 64
#define NQQ 256
#define TOK 32
#define MARGIN 0.16f
#define CAP 32768

typedef __attribute__((ext_vector_type(8))) short bf16x8;
typedef __attribute__((ext_vector_type(4))) float f32x4;

__device__ __forceinline__ unsigned short hi_bf16(float v) {
  unsigned u = __float_as_uint(v);
  return (unsigned short)(((u + 0x7FFFu + ((u >> 16) & 1u)) & 0xFFFF0000u) >> 16);
}

// prep: qk = q @ w_ks (f32, for recheck), bf16 fragments qhf, MT = (w_fc @ w_vs)^T
__global__ __launch_bounds__(256) void prep_kernel(
    const float* __restrict__ q, const float* __restrict__ w_ks,
    const float* __restrict__ w_vs, const float* __restrict__ w_fc,
    float* __restrict__ qk, float* __restrict__ MT,
    unsigned short* __restrict__ qhf) {
  __shared__ float sbuf[DKK];
  const int tid = threadIdx.x;
  const int blk = blockIdx.x;
  if (blk < NQQ) {
    const int s = blk;
    if (tid < DKK) sbuf[tid] = q[s * DKK + tid];
    __syncthreads();
    float acc = 0.f;
#pragma unroll
    for (int k = 0; k < DKK; ++k) acc = fmaf(sbuf[k], w_ks[k * DMODEL + tid], acc);
    qk[s * DMODEL + tid] = acc;
    // B fragment layout: elem idx = ((kstep*16 + stile)*64 + (kg*16 + s15))*8 + jj
    int d = tid;
    int kstep = d >> 5, kg = (d >> 3) & 3, jj = d & 7;
    int stile = s >> 4, s15 = s & 15;
    int e = (((kstep * 16 + stile) * 64) + (kg * 16 + s15)) * 8 + jj;
    qhf[e] = hi_bf16(acc);
  } else {
    const int dm = blk - NQQ;
    if (tid < DVV) sbuf[tid] = w_vs[tid * DMODEL + dm];
    __syncthreads();
    float acc = 0.f;
#pragma unroll
    for (int v = 0; v < DVV; ++v) acc = fmaf(w_fc[tid * DVV + v], sbuf[v], acc);
    MT[dm * DMODEL + tid] = acc;
  }
}

// one k-step: prefetch B for k+1, FENCE, then 8 MFMAs for k (pure bf16-hi product)
#define KSTEP(kk, Bhc, Bhn, PRE)                                                        \
  {                                                                                     \
    if (PRE) {                                                                          \
      _Pragma("unroll")                                                                 \
      for (int j = 0; j < 4; ++j)                                                       \
        Bhn[j] = bh[(((kk) + 1) * 16 + w * 4 + j) * 64 + l];                            \
      __builtin_amdgcn_sched_barrier(0);  /* pin: loads issue before k's MFMAs */       \
    }                                                                                   \
    _Pragma("unroll")                                                                   \
    for (int i = 0; i < 2; ++i) {                                                       \
      bf16x8 Ah = *(const bf16x8*)(&xs_h[(((kk) * 2 + i) * 64 + l) * 8]);               \
      _Pragma("unroll")                                                                 \
      for (int j = 0; j < 4; ++j)                                                       \
        acc[i][j] = __builtin_amdgcn_mfma_f32_16x16x32_bf16(Ah, Bhc[j], acc[i][j], 0, 0, 0); \
    }                                                                                   \
  }

// main: pure-bf16 MFMA scores (B reg-dbuf, sched-fenced), top-2 argmax with WIDE
// margin band -> exact f32 recheck, nontemporal one-hot, idx byte write.
__global__ __launch_bounds__(256, 4) void score_kernel(
    const float* __restrict__ x, const unsigned short* __restrict__ qhf,
    float* __restrict__ hard, unsigned char* __restrict__ idxa,
    unsigned* __restrict__ cnt, unsigned* __restrict__ list) {
  __shared__ unsigned short xs_h[8192];   // [kstep(8)][tile(2)][lane(64)][8] bf16, 16 KB
  __shared__ float rm1[4][TOK];
  __shared__ float rm2[4][TOK];
  __shared__ int   ri1[4][TOK];
  __shared__ int   idx_s[TOK];

  const int tid = threadIdx.x;
  const int w = tid >> 6;       // wave 0..3 -> slot range w*64..w*64+63
  const int l = tid & 63;       // lane
  const int b = blockIdx.y;
  const int n0 = blockIdx.x * TOK;
  const float* xbase = x + ((size_t)b * NN + n0) * DMODEL;
  const float4* xb4 = (const float4*)xbase;

  // ---- stage x tile (32 tok x 256 d) as bf16-hi fragments ----
  {
    const int tok = w * 8 + (l >> 3);          // 32 tokens
    const int r   = l & 7;
    const int kg  = r >> 1;                    // (c4>>1)&3
    const int j0  = (r & 1) * 4;
    const int i   = tok >> 4;
    const int t15 = tok & 15;
#pragma unroll
    for (int it = 0; it < 8; ++it) {
      int c4 = it * 8 + r;                     // kstep = it
      float4 v = xb4[tok * 64 + c4];
      int e = (((it * 2 + i) * 64) + (kg * 16 + t15)) * 8 + j0;
      ushort4 hh;
      hh.x = hi_bf16(v.x); hh.y = hi_bf16(v.y);
      hh.z = hi_bf16(v.z); hh.w = hi_bf16(v.w);
      *(ushort4*)(&xs_h[e]) = hh;
    }
  }

  // ---- preload B fragments for k=0 (overlaps with staging latency) ----
  const bf16x8* bh = (const bf16x8*)qhf;
  bf16x8 BhA[4], BhB[4];
#pragma unroll
  for (int j = 0; j < 4; ++j) BhA[j] = bh[(w * 4 + j) * 64 + l];
  __syncthreads();

  // ---- MFMA: 32 tok x 64 slots per wave; B reg ping-pong hides L2/L3 latency ----
  f32x4 acc[2][4];
#pragma unroll
  for (int i = 0; i < 2; ++i)
#pragma unroll
    for (int j = 0; j < 4; ++j) acc[i][j] = (f32x4){0.f, 0.f, 0.f, 0.f};

  KSTEP(0, BhA, BhB, true)
  KSTEP(1, BhB, BhA, true)
  KSTEP(2, BhA, BhB, true)
  KSTEP(3, BhB, BhA, true)
  KSTEP(4, BhA, BhB, true)
  KSTEP(5, BhB, BhA, true)
  KSTEP(6, BhA, BhB, true)
  KSTEP(7, BhB, BhA, false)

  // ---- per-token top-2 over this wave's 64 slots ----
  // C/D layout: col(slot) = l&15, row(token) = (l>>4)*4 + reg
  const int s15 = l & 15, g4 = l >> 4;
#pragma unroll
  for (int i = 0; i < 2; ++i) {
#pragma unroll
    for (int rr = 0; rr < 4; ++rr) {
      float m1 = acc[i][0][rr];
      int   i1 = w * 64 + s15;
      float m2 = -1e30f;
#pragma unroll
      for (int j = 1; j < 4; ++j) {
        float v = acc[i][j][rr];
        int   s = w * 64 + j * 16 + s15;
        if (v > m1) { m2 = m1; m1 = v; i1 = s; }
        else if (v > m2) m2 = v;
      }
#pragma unroll
      for (int off = 1; off < 16; off <<= 1) {
        float om1 = __shfl_xor(m1, off, 64);
        int   oi1 = __shfl_xor(i1, off, 64);
        float om2 = __shfl_xor(m2, off, 64);
        if (om1 > m1 || (om1 == m1 && oi1 < i1)) { m2 = fmaxf(m1, om2); m1 = om1; i1 = oi1; }
        else { m2 = fmaxf(m2, om1); }
      }
      if (s15 == 0) {
        int t = i * 16 + g4 * 4 + rr;
        rm1[w][t] = m1; rm2[w][t] = m2; ri1[w][t] = i1;
      }
    }
  }
  __syncthreads();

  // ---- cross-wave merge (ascending slot ranges -> first-index tie-break) ----
  if (tid < TOK) {
    float m1 = rm1[0][tid]; int i1 = ri1[0][tid]; float m2 = rm2[0][tid];
#pragma unroll
    for (int ww = 1; ww < 4; ++ww) {
      float om1 = rm1[ww][tid]; int oi1 = ri1[ww][tid]; float om2 = rm2[ww][tid];
      if (om1 > m1) { m2 = fmaxf(m1, om2); m1 = om1; i1 = oi1; }
      else { m2 = fmaxf(m2, om1); }
    }
    idx_s[tid] = i1;
    idxa[(size_t)b * NN + n0 + tid] = (unsigned char)i1;
    if (m1 - m2 <= MARGIN) {   // ambiguous under bf16 error -> exact f32 recheck
      unsigned pos = atomicAdd(cnt, 1u);
      if (pos < CAP) list[pos] = (((unsigned)(b * NN + n0 + tid)) << 8) | (unsigned)i1;
    }
  }
  __syncthreads();

  // ---- one-hot write: nontemporal (don't evict B fragments from L2) ----
  f32x4* hbase = (f32x4*)(hard + ((size_t)b * NN + n0) * NQQ);
#pragma unroll
  for (int it = 0; it < 8; ++it) {
    int u = it * 256 + tid;
    int tk = u >> 6;
    int s0 = (u & 63) * 4;
    int tgt = idx_s[tk];
    f32x4 h;
    h[0] = (s0 + 0 == tgt) ? 1.f : 0.f;
    h[1] = (s0 + 1 == tgt) ? 1.f : 0.f;
    h[2] = (s0 + 2 == tgt) ? 1.f : 0.f;
    h[3] = (s0 + 3 == tgt) ? 1.f : 0.f;
    __builtin_nontemporal_store(h, &hbase[u]);
  }
}

// recheck: exact-f32 scores for ambiguous tokens; patch one-hot + idx byte on flip
__global__ __launch_bounds__(256) void recheck_kernel(
    const float* __restrict__ x, const float* __restrict__ qk,
    const unsigned* __restrict__ cnt, const unsigned* __restrict__ list,
    float* __restrict__ hard, unsigned char* __restrict__ idxa) {
  __shared__ float xrow[DMODEL];
  __shared__ float sv[NQQ];
  __shared__ int   si[NQQ];
  const int tid = threadIdx.x;
  unsigned nc = cnt[0];
  int nA = (int)(nc < (unsigned)CAP ? nc : (unsigned)CAP);
  for (int e = blockIdx.x; e < nA; e += gridDim.x) {
    unsigned pk = list[e];
    int tokid = (int)(pk >> 8);
    int olds  = (int)(pk & 255u);
    const float* xr = x + (size_t)tokid * DMODEL;
    xrow[tid] = xr[tid];
    __syncthreads();
    const float* qr = qk + (size_t)tid * DMODEL;
    float a = 0.f;
#pragma unroll
    for (int d4 = 0; d4 < 64; ++d4) {   // strict sequential-d order (matches exact path)
      float4 qv = *(const float4*)(qr + d4 * 4);
      float4 xv = *(const float4*)(&xrow[d4 * 4]);
      a = fmaf(xv.x, qv.x, a); a = fmaf(xv.y, qv.y, a);
      a = fmaf(xv.z, qv.z, a); a = fmaf(xv.w, qv.w, a);
    }
    sv[tid] = a; si[tid] = tid;
    __syncthreads();
    for (int s = 128; s >= 1; s >>= 1) {
      if (tid < s) {
        float vo = sv[tid + s]; int io = si[tid + s];
        if (vo > sv[tid] || (vo == sv[tid] && io < si[tid])) { sv[tid] = vo; si[tid] = io; }
      }
      __syncthreads();
    }
    int news = si[0];
    if (news != olds && tid == 0) {
      hard[(size_t)tokid * NQQ + olds] = 0.f;
      hard[(size_t)tokid * NQQ + news] = 1.f;
      idxa[tokid] = (unsigned char)news;
    }
    __syncthreads();
  }
}

// reduce v2: compact-then-process. S[b, slot, :] = sum of x rows whose idx==slot.
// block = (b, slot-group of 16); no global atomics; exclusive S region per block.
__global__ __launch_bounds__(512) void reduce_kernel(
    const float* __restrict__ x, const unsigned char* __restrict__ idxa,
    float* __restrict__ S) {
  __shared__ unsigned char  idx_l[NN];        // 8 KB
  __shared__ unsigned short list_l[NN];       // 16 KB (worst-case all tokens one sg)
  __shared__ float accs[2][16][DMODEL];       // 32 KB
  __shared__ unsigned lcnt;
  const int tid = threadIdx.x;
  const int b  = blockIdx.x >> 4;
  const int sg = blockIdx.x & 15;
  const int h  = tid >> 8;                    // half
  const int d  = tid & 255;

  // stage idx bytes (512 x 16B) and keep own 16 bytes in regs
  uint4 myidx = ((const uint4*)(idxa + (size_t)b * NN))[tid];
  ((uint4*)idx_l)[tid] = myidx;
  float* af = &accs[0][0][0];
#pragma unroll
  for (int i = 0; i < 16; ++i) af[i * 512 + tid] = 0.f;
  if (tid == 0) lcnt = 0u;
  __syncthreads();

  // ---- phase 1: parallel compaction of matching token ids ----
  {
    unsigned base = (unsigned)tid * 16u;
    unsigned words[4] = {myidx.x, myidx.y, myidx.z, myidx.w};
#pragma unroll
    for (int wi = 0; wi < 4; ++wi)
#pragma unroll
      for (int j = 0; j < 4; ++j) {
        int s = (words[wi] >> (8 * j)) & 255;
        if ((s >> 4) == sg) {
          unsigned pos = atomicAdd(&lcnt, 1u);
          list_l[pos] = (unsigned short)(base + wi * 4 + j);
        }
      }
  }
  __syncthreads();

  // ---- phase 2: process compacted list, 4-wide load pipeline ----
  const int cnt_ = (int)lcnt;
  const float* xb = x + (size_t)b * NN * DMODEL + d;
  float* myacc = &accs[h][0][0] + d;
  int start = (h * cnt_) >> 1;
  int end   = ((h + 1) * cnt_) >> 1;
  int i = start;
  for (; i + 4 <= end; i += 4) {
    int na = list_l[i], nb = list_l[i + 1], nc = list_l[i + 2], nd = list_l[i + 3];
    float va = xb[(size_t)na * DMODEL];
    float vb = xb[(size_t)nb * DMODEL];
    float vc = xb[(size_t)nc * DMODEL];
    float vd = xb[(size_t)nd * DMODEL];
    myacc[(idx_l[na] & 15) * DMODEL] += va;
    myacc[(idx_l[nb] & 15) * DMODEL] += vb;
    myacc[(idx_l[nc] & 15) * DMODEL] += vc;
    myacc[(idx_l[nd] & 15) * DMODEL] += vd;
  }
  for (; i < end; ++i) {
    int n = list_l[i];
    myacc[(idx_l[n] & 15) * DMODEL] += xb[(size_t)n * DMODEL];
  }
  __syncthreads();

  // ---- write S (exclusive region): 16 rows x 256 ----
#pragma unroll
  for (int ii = 0; ii < 8; ++ii) {
    int u = ii * 512 + tid;
    int ss = u >> 8, dd = u & 255;
    S[((size_t)b * NQQ + sg * 16 + ss) * DMODEL + dd] = accs[0][ss][dd] + accs[1][ss][dd];
  }
}

// out[b,s,d] = sum_dm S[b,s,dm] * MT[dm,d]
__global__ __launch_bounds__(256) void out_kernel(
    const float* __restrict__ S, const float* __restrict__ MT,
    float* __restrict__ out) {
  __shared__ float srow[8][DMODEL];
  const int tid = threadIdx.x;
  const int r0 = blockIdx.x * 8;
#pragma unroll
  for (int i = 0; i < 8; ++i) srow[i][tid] = S[(size_t)(r0 + i) * DMODEL + tid];
  __syncthreads();
  float a[8];
#pragma unroll
  for (int i = 0; i < 8; ++i) a[i] = 0.f;
  for (int dm = 0; dm < DMODEL; ++dm) {
    float m = MT[(size_t)dm * DMODEL + tid];
#pragma unroll
    for (int i = 0; i < 8; ++i) a[i] = fmaf(srow[i][dm], m, a[i]);
  }
#pragma unroll
  for (int i = 0; i < 8; ++i) out[(size_t)(r0 + i) * DMODEL + tid] = a[i];
}

extern "C" void kernel_launch(void* const* d_in, const int* in_sizes, int n_in,
                              void* d_out, int out_size, void* d_ws, size_t ws_size,
                              hipStream_t stream) {
  const float* x   = (const float*)d_in[0];
  const float* q   = (const float*)d_in[1];
  const float* wks = (const float*)d_in[2];
  const float* wvs = (const float*)d_in[3];
  const float* wfc = (const float*)d_in[4];

  float* out  = (float*)d_out;                       // (16,256,256)
  float* hard = out + (size_t)BB * NQQ * DMODEL;     // (16,8192,256)

  float* qk = (float*)d_ws;                          // 65536 f
  float* MT = qk + 65536;                            // 65536 f
  float* S  = MT + 65536;                            // 1048576 f (4 MB)
  unsigned* cnt  = (unsigned*)(S + 1048576);         // 64 u32 (pad)
  unsigned* list = cnt + 64;                         // CAP u32
  unsigned short* qhf = (unsigned short*)(list + CAP);   // 65536 bf16
  unsigned char*  idxa = (unsigned char*)(qhf + 131072); // 131072 bytes

  (void)hipMemsetAsync(cnt, 0, 256, stream);
  prep_kernel<<<2 * NQQ, 256, 0, stream>>>(q, wks, wvs, wfc, qk, MT, qhf);
  score_kernel<<<dim3(NN / TOK, BB), 256, 0, stream>>>(x, qhf, hard, idxa, cnt, list);
  recheck_kernel<<<2048, 256, 0, stream>>>(x, qk, cnt, list, hard, idxa);
  reduce_kernel<<<BB * 16, 512, 0, stream>>>(x, idxa, S);
  out_kernel<<<(BB * NQQ) / 8, 256, 0, stream>>>(S, MT, out);
}

// Round 14
// 188.429 us; speedup vs baseline: 1.4787x; 1.4787x over previous
//
#include <hip/hip_runtime.h>

#define BB 16
#define NN 8192
#define DMODEL 256
#define DKK 64
#define DVV 64
#define NQQ 256
#define TOK 32
#define MARGIN 0.16f
#define CAPP 131072
#define CAPF 131072
#define FB 16

typedef __attribute__((ext_vector_type(8))) short bf16x8;
typedef __attribute__((ext_vector_type(4))) float f32x4;

__device__ __forceinline__ unsigned short hi_bf16(float v) {
  unsigned u = __float_as_uint(v);
  return (unsigned short)(((u + 0x7FFFu + ((u >> 16) & 1u)) & 0xFFFF0000u) >> 16);
}

// prep: qk = q @ w_ks (f32, for recheck), bf16 fragments qhf, MT = (w_fc @ w_vs)^T
__global__ __launch_bounds__(256) void prep_kernel(
    const float* __restrict__ q, const float* __restrict__ w_ks,
    const float* __restrict__ w_vs, const float* __restrict__ w_fc,
    float* __restrict__ qk, float* __restrict__ MT,
    unsigned short* __restrict__ qhf) {
  __shared__ float sbuf[DKK];
  const int tid = threadIdx.x;
  const int blk = blockIdx.x;
  if (blk < NQQ) {
    const int s = blk;
    if (tid < DKK) sbuf[tid] = q[s * DKK + tid];
    __syncthreads();
    float acc = 0.f;
#pragma unroll
    for (int k = 0; k < DKK; ++k) acc = fmaf(sbuf[k], w_ks[k * DMODEL + tid], acc);
    qk[s * DMODEL + tid] = acc;
    int d = tid;
    int kstep = d >> 5, kg = (d >> 3) & 3, jj = d & 7;
    int stile = s >> 4, s15 = s & 15;
    int e = (((kstep * 16 + stile) * 64) + (kg * 16 + s15)) * 8 + jj;
    qhf[e] = hi_bf16(acc);
  } else {
    const int dm = blk - NQQ;
    if (tid < DVV) sbuf[tid] = w_vs[tid * DMODEL + dm];
    __syncthreads();
    float acc = 0.f;
#pragma unroll
    for (int v = 0; v < DVV; ++v) acc = fmaf(w_fc[tid * DVV + v], sbuf[v], acc);
    MT[dm * DMODEL + tid] = acc;
  }
}

// one k-step: prefetch B for k+1, FENCE, then 8 MFMAs for k
#define KSTEP(kk, Bhc, Bhn, PRE)                                                        \
  {                                                                                     \
    if (PRE) {                                                                          \
      _Pragma("unroll")                                                                 \
      for (int j = 0; j < 4; ++j)                                                       \
        Bhn[j] = bh[(((kk) + 1) * 16 + w * 4 + j) * 64 + l];                            \
      __builtin_amdgcn_sched_barrier(0);                                                \
    }                                                                                   \
    _Pragma("unroll")                                                                   \
    for (int i = 0; i < 2; ++i) {                                                       \
      bf16x8 Ah = *(const bf16x8*)(&xs_h[(((kk) * 2 + i) * 64 + l) * 8]);               \
      _Pragma("unroll")                                                                 \
      for (int j = 0; j < 4; ++j)                                                       \
        acc[i][j] = __builtin_amdgcn_mfma_f32_16x16x32_bf16(Ah, Bhc[j], acc[i][j], 0, 0, 0); \
    }                                                                                   \
  }

// main: bf16 MFMA scores, top-2 (with i2) + band count -> pair/full flag lists,
// nontemporal one-hot, idx byte write.
__global__ __launch_bounds__(256, 4) void score_kernel(
    const float* __restrict__ x, const unsigned short* __restrict__ qhf,
    float* __restrict__ hard, unsigned char* __restrict__ idxa,
    unsigned* __restrict__ cnt, uint2* __restrict__ listP,
    unsigned* __restrict__ listF) {
  __shared__ unsigned short xs_h[8192];   // 16 KB
  __shared__ float rm1[4][TOK], rm2[4][TOK];
  __shared__ int   ri1[4][TOK], ri2[4][TOK];
  __shared__ int   idx_s[TOK];
  __shared__ float bm1[TOK];
  __shared__ int   rcnt[4][TOK];

  const int tid = threadIdx.x;
  const int w = tid >> 6;
  const int l = tid & 63;
  const int b = blockIdx.y;
  const int n0 = blockIdx.x * TOK;
  const float* xbase = x + ((size_t)b * NN + n0) * DMODEL;
  const float4* xb4 = (const float4*)xbase;

  // ---- stage x tile as bf16-hi fragments ----
  {
    const int tok = w * 8 + (l >> 3);
    const int r   = l & 7;
    const int kg  = r >> 1;
    const int j0  = (r & 1) * 4;
    const int i   = tok >> 4;
    const int t15 = tok & 15;
#pragma unroll
    for (int it = 0; it < 8; ++it) {
      int c4 = it * 8 + r;
      float4 v = xb4[tok * 64 + c4];
      int e = (((it * 2 + i) * 64) + (kg * 16 + t15)) * 8 + j0;
      ushort4 hh;
      hh.x = hi_bf16(v.x); hh.y = hi_bf16(v.y);
      hh.z = hi_bf16(v.z); hh.w = hi_bf16(v.w);
      *(ushort4*)(&xs_h[e]) = hh;
    }
  }

  const bf16x8* bh = (const bf16x8*)qhf;
  bf16x8 BhA[4], BhB[4];
#pragma unroll
  for (int j = 0; j < 4; ++j) BhA[j] = bh[(w * 4 + j) * 64 + l];
  __syncthreads();

  f32x4 acc[2][4];
#pragma unroll
  for (int i = 0; i < 2; ++i)
#pragma unroll
    for (int j = 0; j < 4; ++j) acc[i][j] = (f32x4){0.f, 0.f, 0.f, 0.f};

  KSTEP(0, BhA, BhB, true)
  KSTEP(1, BhB, BhA, true)
  KSTEP(2, BhA, BhB, true)
  KSTEP(3, BhB, BhA, true)
  KSTEP(4, BhA, BhB, true)
  KSTEP(5, BhB, BhA, true)
  KSTEP(6, BhA, BhB, true)
  KSTEP(7, BhB, BhA, false)

  // ---- per-token top-2 (value+index both) over this wave's 64 slots ----
  const int s15 = l & 15, g4 = l >> 4;
#pragma unroll
  for (int i = 0; i < 2; ++i) {
#pragma unroll
    for (int rr = 0; rr < 4; ++rr) {
      float m1 = acc[i][0][rr];
      int   i1 = w * 64 + s15;
      float m2 = -1e30f;
      int   i2 = -1;
#pragma unroll
      for (int j = 1; j < 4; ++j) {
        float v = acc[i][j][rr];
        int   s = w * 64 + j * 16 + s15;
        if (v > m1) { m2 = m1; i2 = i1; m1 = v; i1 = s; }
        else if (v > m2) { m2 = v; i2 = s; }
      }
#pragma unroll
      for (int off = 1; off < 16; off <<= 1) {
        float om1 = __shfl_xor(m1, off, 64);
        int   oi1 = __shfl_xor(i1, off, 64);
        float om2 = __shfl_xor(m2, off, 64);
        int   oi2 = __shfl_xor(i2, off, 64);
        if (om1 > m1 || (om1 == m1 && oi1 < i1)) {
          if (m1 > om2 || (m1 == om2 && i1 < oi2)) { m2 = m1; i2 = i1; }
          else { m2 = om2; i2 = oi2; }
          m1 = om1; i1 = oi1;
        } else {
          if (om1 > m2 || (om1 == m2 && oi1 < i2)) { m2 = om1; i2 = oi1; }
        }
      }
      if (s15 == 0) {
        int t = i * 16 + g4 * 4 + rr;
        rm1[w][t] = m1; rm2[w][t] = m2; ri1[w][t] = i1; ri2[w][t] = i2;
      }
    }
  }
  __syncthreads();

  // ---- cross-wave merge; keep (m1,i1,m2,i2) in registers of tid<TOK ----
  float fm1 = 0.f; int fi1 = 0, fi2 = 0;
  if (tid < TOK) {
    float m1 = rm1[0][tid]; int i1 = ri1[0][tid];
    float m2 = rm2[0][tid]; int i2 = ri2[0][tid];
#pragma unroll
    for (int ww = 1; ww < 4; ++ww) {
      float om1 = rm1[ww][tid]; int oi1 = ri1[ww][tid];
      float om2 = rm2[ww][tid]; int oi2 = ri2[ww][tid];
      if (om1 > m1 || (om1 == m1 && oi1 < i1)) {
        if (m1 > om2 || (m1 == om2 && i1 < oi2)) { m2 = m1; i2 = i1; }
        else { m2 = om2; i2 = oi2; }
        m1 = om1; i1 = oi1;
      } else {
        if (om1 > m2 || (om1 == m2 && oi1 < i2)) { m2 = om1; i2 = oi1; }
      }
    }
    fm1 = m1; fi1 = i1; fi2 = i2;
    idx_s[tid] = i1;
    bm1[tid] = m1;
    idxa[(size_t)b * NN + n0 + tid] = (unsigned char)i1;
  }
  __syncthreads();

  // ---- band count: slots with score >= m1 - MARGIN (includes i1) ----
#pragma unroll
  for (int i = 0; i < 2; ++i) {
#pragma unroll
    for (int rr = 0; rr < 4; ++rr) {
      int t = i * 16 + g4 * 4 + rr;
      float thr = bm1[t] - MARGIN;
      int c = 0;
#pragma unroll
      for (int j = 0; j < 4; ++j) c += (acc[i][j][rr] >= thr) ? 1 : 0;
#pragma unroll
      for (int off = 1; off < 16; off <<= 1) c += __shfl_xor(c, off, 64);
      if (s15 == 0) rcnt[w][t] = c;
    }
  }
  __syncthreads();

  // ---- flag: band==2 -> pair list; band>=3 -> full list ----
  if (tid < TOK) {
    int band = rcnt[0][tid] + rcnt[1][tid] + rcnt[2][tid] + rcnt[3][tid];
    int tokid = b * NN + n0 + tid;
    if (band == 2) {
      unsigned pos = atomicAdd(&cnt[0], 1u);
      if (pos < CAPP) listP[pos] = (uint2){(unsigned)tokid, (unsigned)(fi1 | (fi2 << 8))};
    } else if (band >= 3) {
      unsigned pos = atomicAdd(&cnt[1], 1u);
      if (pos < CAPF) listF[pos] = (unsigned)tokid;
    }
    (void)fm1;
  }
  __syncthreads();

  // ---- one-hot write: nontemporal ----
  f32x4* hbase = (f32x4*)(hard + ((size_t)b * NN + n0) * NQQ);
#pragma unroll
  for (int it = 0; it < 8; ++it) {
    int u = it * 256 + tid;
    int tk = u >> 6;
    int s0 = (u & 63) * 4;
    int tgt = idx_s[tk];
    f32x4 h;
    h[0] = (s0 + 0 == tgt) ? 1.f : 0.f;
    h[1] = (s0 + 1 == tgt) ? 1.f : 0.f;
    h[2] = (s0 + 2 == tgt) ? 1.f : 0.f;
    h[3] = (s0 + 3 == tgt) ? 1.f : 0.f;
    __builtin_nontemporal_store(h, &hbase[u]);
  }
}

// pair recheck: one wave per token; exact f32 dots for the two candidates only.
__global__ __launch_bounds__(256) void paircheck_kernel(
    const float* __restrict__ x, const float* __restrict__ qk,
    const unsigned* __restrict__ cnt, const uint2* __restrict__ listP,
    float* __restrict__ hard, unsigned char* __restrict__ idxa) {
  const int wid = blockIdx.x * 4 + (threadIdx.x >> 6);
  const int l = threadIdx.x & 63;
  const int nw = gridDim.x * 4;
  unsigned n = cnt[0]; if (n > (unsigned)CAPP) n = CAPP;
  for (int e = wid; e < (int)n; e += nw) {
    uint2 pk = listP[e];
    int tok = (int)pk.x;
    int i1 = (int)(pk.y & 255u), i2 = (int)((pk.y >> 8) & 255u);
    float4 xv = ((const float4*)(x + (size_t)tok * DMODEL))[l];
    float4 a  = ((const float4*)(qk + (size_t)i1 * DMODEL))[l];
    float4 bq = ((const float4*)(qk + (size_t)i2 * DMODEL))[l];
    float p1 = xv.x * a.x;  p1 = fmaf(xv.y, a.y, p1);
    p1 = fmaf(xv.z, a.z, p1); p1 = fmaf(xv.w, a.w, p1);
    float p2 = xv.x * bq.x; p2 = fmaf(xv.y, bq.y, p2);
    p2 = fmaf(xv.z, bq.z, p2); p2 = fmaf(xv.w, bq.w, p2);
#pragma unroll
    for (int off = 32; off >= 1; off >>= 1) {
      p1 += __shfl_xor(p1, off, 64);
      p2 += __shfl_xor(p2, off, 64);
    }
    if (l == 0) {
      int news = (p2 > p1 || (p2 == p1 && i2 < i1)) ? i2 : i1;
      if (news != i1) {
        hard[(size_t)tok * NQQ + i1] = 0.f;
        hard[(size_t)tok * NQQ + news] = 1.f;
        idxa[tok] = (unsigned char)news;
      }
    }
  }
}

// full recheck: batched FB tokens per block-iter; one qk sweep shared by all FB.
__global__ __launch_bounds__(256) void fullcheck_kernel(
    const float* __restrict__ x, const float* __restrict__ qk,
    const unsigned* __restrict__ cnt, const unsigned* __restrict__ listF,
    float* __restrict__ hard, unsigned char* __restrict__ idxa) {
  __shared__ float xs[FB][DMODEL];   // 16 KB
  __shared__ float sco[FB][NQQ];     // 16 KB
  __shared__ int   toks[FB];
  const int tid = threadIdx.x;
  unsigned n = cnt[1]; if (n > (unsigned)CAPF) n = CAPF;
  int nb = ((int)n + FB - 1) / FB;
  for (int batch = blockIdx.x; batch < nb; batch += gridDim.x) {
    int base = batch * FB;
    if (tid < FB) {
      int ei = base + tid;
      if (ei >= (int)n) ei = base;     // pad: duplicate first entry (idempotent)
      toks[tid] = (int)listF[ei];
    }
    __syncthreads();
#pragma unroll
    for (int t = 0; t < FB; ++t) xs[t][tid] = x[(size_t)toks[t] * DMODEL + tid];
    __syncthreads();
    float accv[FB];
#pragma unroll
    for (int t = 0; t < FB; ++t) accv[t] = 0.f;
    const float4* qrow = (const float4*)(qk + (size_t)tid * DMODEL);
    for (int d4 = 0; d4 < 64; ++d4) {
      float4 qv = qrow[d4];
#pragma unroll
      for (int t = 0; t < FB; ++t) {
        float4 xv = *(const float4*)(&xs[t][d4 * 4]);
        accv[t] = fmaf(qv.x, xv.x, accv[t]);
        accv[t] = fmaf(qv.y, xv.y, accv[t]);
        accv[t] = fmaf(qv.z, xv.z, accv[t]);
        accv[t] = fmaf(qv.w, xv.w, accv[t]);
      }
    }
#pragma unroll
    for (int t = 0; t < FB; ++t) sco[t][tid] = accv[t];
    __syncthreads();
    // 16 groups of 16 threads: group g reduces token g's 256 scores
    {
      int g = tid >> 4, j = tid & 15;
      float bv = -1e30f; int bs = 256;
#pragma unroll
      for (int k = 0; k < 16; ++k) {
        int s = j + k * 16;
        float v = sco[g][s];
        if (v > bv) { bv = v; bs = s; }
      }
#pragma unroll
      for (int off = 1; off < 16; off <<= 1) {
        float ov = __shfl_xor(bv, off, 64);
        int   os = __shfl_xor(bs, off, 64);
        if (ov > bv || (ov == bv && os < bs)) { bv = ov; bs = os; }
      }
      if (j == 0) {
        int tok = toks[g];
        int olds = (int)idxa[tok];
        if (bs != olds) {
          hard[(size_t)tok * NQQ + olds] = 0.f;
          hard[(size_t)tok * NQQ + bs] = 1.f;
          idxa[tok] = (unsigned char)bs;
        }
      }
    }
    __syncthreads();
  }
}

// reduce: compact-then-process. S[b, slot, :] = sum of x rows whose idx==slot.
__global__ __launch_bounds__(512) void reduce_kernel(
    const float* __restrict__ x, const unsigned char* __restrict__ idxa,
    float* __restrict__ S) {
  __shared__ unsigned char  idx_l[NN];
  __shared__ unsigned short list_l[NN];
  __shared__ float accs[2][16][DMODEL];
  __shared__ unsigned lcnt;
  const int tid = threadIdx.x;
  const int b  = blockIdx.x >> 4;
  const int sg = blockIdx.x & 15;
  const int h  = tid >> 8;
  const int d  = tid & 255;

  uint4 myidx = ((const uint4*)(idxa + (size_t)b * NN))[tid];
  ((uint4*)idx_l)[tid] = myidx;
  float* af = &accs[0][0][0];
#pragma unroll
  for (int i = 0; i < 16; ++i) af[i * 512 + tid] = 0.f;
  if (tid == 0) lcnt = 0u;
  __syncthreads();

  {
    unsigned base = (unsigned)tid * 16u;
    unsigned words[4] = {myidx.x, myidx.y, myidx.z, myidx.w};
#pragma unroll
    for (int wi = 0; wi < 4; ++wi)
#pragma unroll
      for (int j = 0; j < 4; ++j) {
        int s = (words[wi] >> (8 * j)) & 255;
        if ((s >> 4) == sg) {
          unsigned pos = atomicAdd(&lcnt, 1u);
          list_l[pos] = (unsigned short)(base + wi * 4 + j);
        }
      }
  }
  __syncthreads();

  const int cnt_ = (int)lcnt;
  const float* xb = x + (size_t)b * NN * DMODEL + d;
  float* myacc = &accs[h][0][0] + d;
  int start = (h * cnt_) >> 1;
  int end   = ((h + 1) * cnt_) >> 1;
  int i = start;
  for (; i + 4 <= end; i += 4) {
    int na = list_l[i], nb2 = list_l[i + 1], nc = list_l[i + 2], nd = list_l[i + 3];
    float va = xb[(size_t)na * DMODEL];
    float vb = xb[(size_t)nb2 * DMODEL];
    float vc = xb[(size_t)nc * DMODEL];
    float vd = xb[(size_t)nd * DMODEL];
    myacc[(idx_l[na] & 15) * DMODEL] += va;
    myacc[(idx_l[nb2] & 15) * DMODEL] += vb;
    myacc[(idx_l[nc] & 15) * DMODEL] += vc;
    myacc[(idx_l[nd] & 15) * DMODEL] += vd;
  }
  for (; i < end; ++i) {
    int nn = list_l[i];
    myacc[(idx_l[nn] & 15) * DMODEL] += xb[(size_t)nn * DMODEL];
  }
  __syncthreads();

#pragma unroll
  for (int ii = 0; ii < 8; ++ii) {
    int u = ii * 512 + tid;
    int ss = u >> 8, dd = u & 255;
    S[((size_t)b * NQQ + sg * 16 + ss) * DMODEL + dd] = accs[0][ss][dd] + accs[1][ss][dd];
  }
}

// out[b,s,d] = sum_dm S[b,s,dm] * MT[dm,d]
__global__ __launch_bounds__(256) void out_kernel(
    const float* __restrict__ S, const float* __restrict__ MT,
    float* __restrict__ out) {
  __shared__ float srow[8][DMODEL];
  const int tid = threadIdx.x;
  const int r0 = blockIdx.x * 8;
#pragma unroll
  for (int i = 0; i < 8; ++i) srow[i][tid] = S[(size_t)(r0 + i) * DMODEL + tid];
  __syncthreads();
  float a[8];
#pragma unroll
  for (int i = 0; i < 8; ++i) a[i] = 0.f;
  for (int dm = 0; dm < DMODEL; ++dm) {
    float m = MT[(size_t)dm * DMODEL + tid];
#pragma unroll
    for (int i = 0; i < 8; ++i) a[i] = fmaf(srow[i][dm], m, a[i]);
  }
#pragma unroll
  for (int i = 0; i < 8; ++i) out[(size_t)(r0 + i) * DMODEL + tid] = a[i];
}

extern "C" void kernel_launch(void* const* d_in, const int* in_sizes, int n_in,
                              void* d_out, int out_size, void* d_ws, size_t ws_size,
                              hipStream_t stream) {
  const float* x   = (const float*)d_in[0];
  const float* q   = (const float*)d_in[1];
  const float* wks = (const float*)d_in[2];
  const float* wvs = (const float*)d_in[3];
  const float* wfc = (const float*)d_in[4];

  float* out  = (float*)d_out;                       // (16,256,256)
  float* hard = out + (size_t)BB * NQQ * DMODEL;     // (16,8192,256)

  float* qk = (float*)d_ws;                          // 256 KB
  float* MT = qk + 65536;                            // 256 KB
  float* S  = MT + 65536;                            // 4 MB
  unsigned* cnt  = (unsigned*)(S + 1048576);         // 256 B
  uint2*    listP = (uint2*)(cnt + 64);              // 1 MB
  unsigned* listF = (unsigned*)(listP + CAPP);       // 512 KB
  unsigned short* qhf = (unsigned short*)(listF + CAPF);  // 128 KB
  unsigned char*  idxa = (unsigned char*)(qhf + 65536);   // 128 KB

  (void)hipMemsetAsync(cnt, 0, 256, stream);
  prep_kernel<<<2 * NQQ, 256, 0, stream>>>(q, wks, wvs, wfc, qk, MT, qhf);
  score_kernel<<<dim3(NN / TOK, BB), 256, 0, stream>>>(x, qhf, hard, idxa, cnt, listP, listF);
  paircheck_kernel<<<2048, 256, 0, stream>>>(x, qk, cnt, listP, hard, idxa);
  fullcheck_kernel<<<2048, 256, 0, stream>>>(x, qk, cnt, listF, hard, idxa);
  reduce_kernel<<<BB * 16, 512, 0, stream>>>(x, idxa, S);
  out_kernel<<<(BB * NQQ) / 8, 256, 0, stream>>>(S, MT, out);
}

// Round 15
// 169.457 us; speedup vs baseline: 1.6443x; 1.1120x over previous
//
#include <hip/hip_runtime.h>

#define BB 16
#define NN 8192
#define DMODEL 256
#define DKK 64
#define DVV 64
#define NQQ 256
#define TOK 32
#define MARGIN 0.16f
#define CAPF 131072
#define FB 16

typedef __attribute__((ext_vector_type(8))) short bf16x8;
typedef __attribute__((ext_vector_type(4))) float f32x4;

__device__ __forceinline__ unsigned short hi_bf16(float v) {
  unsigned u = __float_as_uint(v);
  return (unsigned short)(((u + 0x7FFFu + ((u >> 16) & 1u)) & 0xFFFF0000u) >> 16);
}

// prep: qk = q @ w_ks (f32, for recheck), bf16 fragments qhf, MT = (w_fc @ w_vs)^T
__global__ __launch_bounds__(256) void prep_kernel(
    const float* __restrict__ q, const float* __restrict__ w_ks,
    const float* __restrict__ w_vs, const float* __restrict__ w_fc,
    float* __restrict__ qk, float* __restrict__ MT,
    unsigned short* __restrict__ qhf) {
  __shared__ float sbuf[DKK];
  const int tid = threadIdx.x;
  const int blk = blockIdx.x;
  if (blk < NQQ) {
    const int s = blk;
    if (tid < DKK) sbuf[tid] = q[s * DKK + tid];
    __syncthreads();
    float acc = 0.f;
#pragma unroll
    for (int k = 0; k < DKK; ++k) acc = fmaf(sbuf[k], w_ks[k * DMODEL + tid], acc);
    qk[s * DMODEL + tid] = acc;
    int d = tid;
    int kstep = d >> 5, kg = (d >> 3) & 3, jj = d & 7;
    int stile = s >> 4, s15 = s & 15;
    int e = (((kstep * 16 + stile) * 64) + (kg * 16 + s15)) * 8 + jj;
    qhf[e] = hi_bf16(acc);
  } else {
    const int dm = blk - NQQ;
    if (tid < DVV) sbuf[tid] = w_vs[tid * DMODEL + dm];
    __syncthreads();
    float acc = 0.f;
#pragma unroll
    for (int v = 0; v < DVV; ++v) acc = fmaf(w_fc[tid * DVV + v], sbuf[v], acc);
    MT[dm * DMODEL + tid] = acc;
  }
}

// one k-step: prefetch B for k+1, FENCE, then 8 MFMAs for k
#define KSTEP(kk, Bhc, Bhn, PRE)                                                        \
  {                                                                                     \
    if (PRE) {                                                                          \
      _Pragma("unroll")                                                                 \
      for (int j = 0; j < 4; ++j)                                                       \
        Bhn[j] = bh[(((kk) + 1) * 16 + w * 4 + j) * 64 + l];                            \
      __builtin_amdgcn_sched_barrier(0);                                                \
    }                                                                                   \
    _Pragma("unroll")                                                                   \
    for (int i = 0; i < 2; ++i) {                                                       \
      bf16x8 Ah = *(const bf16x8*)(&xs_h[(((kk) * 2 + i) * 64 + l) * 8]);               \
      _Pragma("unroll")                                                                 \
      for (int j = 0; j < 4; ++j)                                                       \
        acc[i][j] = __builtin_amdgcn_mfma_f32_16x16x32_bf16(Ah, Bhc[j], acc[i][j], 0, 0, 0); \
    }                                                                                   \
  }

// main: bf16 MFMA scores; lean argmax (max-reduce -> gmax -> index+band rescan);
// flagged (band>=2) tokens -> batched fullcheck; nontemporal one-hot; idx byte.
__global__ __launch_bounds__(256, 4) void score_kernel(
    const float* __restrict__ x, const unsigned short* __restrict__ qhf,
    float* __restrict__ hard, unsigned char* __restrict__ idxa,
    unsigned* __restrict__ cnt, unsigned* __restrict__ listF) {
  __shared__ unsigned short xs_h[8192];   // 16 KB
  __shared__ float rm1[4][TOK];
  __shared__ int   ri1[4][TOK];
  __shared__ int   rcnt[4][TOK];
  __shared__ float bm1[TOK];
  __shared__ int   idx_s[TOK];

  const int tid = threadIdx.x;
  const int w = tid >> 6;
  const int l = tid & 63;
  const int b = blockIdx.y;
  const int n0 = blockIdx.x * TOK;
  const float* xbase = x + ((size_t)b * NN + n0) * DMODEL;
  const float4* xb4 = (const float4*)xbase;

  // ---- stage x tile as bf16-hi fragments ----
  {
    const int tok = w * 8 + (l >> 3);
    const int r   = l & 7;
    const int kg  = r >> 1;
    const int j0  = (r & 1) * 4;
    const int i   = tok >> 4;
    const int t15 = tok & 15;
#pragma unroll
    for (int it = 0; it < 8; ++it) {
      int c4 = it * 8 + r;
      float4 v = xb4[tok * 64 + c4];
      int e = (((it * 2 + i) * 64) + (kg * 16 + t15)) * 8 + j0;
      ushort4 hh;
      hh.x = hi_bf16(v.x); hh.y = hi_bf16(v.y);
      hh.z = hi_bf16(v.z); hh.w = hi_bf16(v.w);
      *(ushort4*)(&xs_h[e]) = hh;
    }
  }

  const bf16x8* bh = (const bf16x8*)qhf;
  bf16x8 BhA[4], BhB[4];
#pragma unroll
  for (int j = 0; j < 4; ++j) BhA[j] = bh[(w * 4 + j) * 64 + l];
  __syncthreads();

  f32x4 acc[2][4];
#pragma unroll
  for (int i = 0; i < 2; ++i)
#pragma unroll
    for (int j = 0; j < 4; ++j) acc[i][j] = (f32x4){0.f, 0.f, 0.f, 0.f};

  KSTEP(0, BhA, BhB, true)
  KSTEP(1, BhB, BhA, true)
  KSTEP(2, BhA, BhB, true)
  KSTEP(3, BhB, BhA, true)
  KSTEP(4, BhA, BhB, true)
  KSTEP(5, BhB, BhA, true)
  KSTEP(6, BhA, BhB, true)
  KSTEP(7, BhB, BhA, false)

  const int s15 = l & 15, g4 = l >> 4;

  // ---- pass A: per-wave value-only max over this wave's 64 slots ----
#pragma unroll
  for (int i = 0; i < 2; ++i) {
#pragma unroll
    for (int rr = 0; rr < 4; ++rr) {
      float m = fmaxf(fmaxf(acc[i][0][rr], acc[i][1][rr]),
                      fmaxf(acc[i][2][rr], acc[i][3][rr]));
#pragma unroll
      for (int off = 1; off < 16; off <<= 1)
        m = fmaxf(m, __shfl_xor(m, off, 64));
      if (s15 == 0) rm1[w][i * 16 + g4 * 4 + rr] = m;
    }
  }
  __syncthreads();

  // ---- global max per token ----
  if (tid < TOK)
    bm1[tid] = fmaxf(fmaxf(rm1[0][tid], rm1[1][tid]),
                     fmaxf(rm1[2][tid], rm1[3][tid]));
  __syncthreads();

  // ---- pass B: first-index of gmax + band count (>= gmax - MARGIN) ----
#pragma unroll
  for (int i = 0; i < 2; ++i) {
#pragma unroll
    for (int rr = 0; rr < 4; ++rr) {
      int t = i * 16 + g4 * 4 + rr;
      float gm = bm1[t];
      float thr = gm - MARGIN;
      int c = 0;
      int im = 1024;
#pragma unroll
      for (int j = 0; j < 4; ++j) {
        float v = acc[i][j][rr];
        c += (v >= thr) ? 1 : 0;
        int s = w * 64 + j * 16 + s15;
        if (v == gm && s < im) im = s;
      }
#pragma unroll
      for (int off = 1; off < 16; off <<= 1) {
        c += __shfl_xor(c, off, 64);
        int oim = __shfl_xor(im, off, 64);
        im = min(im, oim);
      }
      if (s15 == 0) { rcnt[w][t] = c; ri1[w][t] = im; }
    }
  }
  __syncthreads();

  // ---- final: i1 = min matching index across waves; flag if band >= 2 ----
  if (tid < TOK) {
    int i1 = min(min(ri1[0][tid], ri1[1][tid]), min(ri1[2][tid], ri1[3][tid]));
    int band = rcnt[0][tid] + rcnt[1][tid] + rcnt[2][tid] + rcnt[3][tid];
    idx_s[tid] = i1;
    idxa[(size_t)b * NN + n0 + tid] = (unsigned char)i1;
    if (band >= 2) {
      unsigned pos = atomicAdd(cnt, 1u);
      if (pos < CAPF) listF[pos] = (unsigned)(b * NN + n0 + tid);
    }
  }
  __syncthreads();

  // ---- one-hot write: nontemporal ----
  f32x4* hbase = (f32x4*)(hard + ((size_t)b * NN + n0) * NQQ);
#pragma unroll
  for (int it = 0; it < 8; ++it) {
    int u = it * 256 + tid;
    int tk = u >> 6;
    int s0 = (u & 63) * 4;
    int tgt = idx_s[tk];
    f32x4 h;
    h[0] = (s0 + 0 == tgt) ? 1.f : 0.f;
    h[1] = (s0 + 1 == tgt) ? 1.f : 0.f;
    h[2] = (s0 + 2 == tgt) ? 1.f : 0.f;
    h[3] = (s0 + 3 == tgt) ? 1.f : 0.f;
    __builtin_nontemporal_store(h, &hbase[u]);
  }
}

// full recheck: batched FB tokens per block-iter; one qk sweep shared by all FB.
__global__ __launch_bounds__(256) void fullcheck_kernel(
    const float* __restrict__ x, const float* __restrict__ qk,
    const unsigned* __restrict__ cnt, const unsigned* __restrict__ listF,
    float* __restrict__ hard, unsigned char* __restrict__ idxa) {
  __shared__ float xs[FB][DMODEL];   // 16 KB
  __shared__ float sco[FB][NQQ];     // 16 KB
  __shared__ int   toks[FB];
  const int tid = threadIdx.x;
  unsigned n = cnt[0]; if (n > (unsigned)CAPF) n = CAPF;
  int nb = ((int)n + FB - 1) / FB;
  for (int batch = blockIdx.x; batch < nb; batch += gridDim.x) {
    int base = batch * FB;
    if (tid < FB) {
      int ei = base + tid;
      if (ei >= (int)n) ei = base;     // pad: duplicate first entry (idempotent)
      toks[tid] = (int)listF[ei];
    }
    __syncthreads();
#pragma unroll
    for (int t = 0; t < FB; ++t) xs[t][tid] = x[(size_t)toks[t] * DMODEL + tid];
    __syncthreads();
    float accv[FB];
#pragma unroll
    for (int t = 0; t < FB; ++t) accv[t] = 0.f;
    const float4* qrow = (const float4*)(qk + (size_t)tid * DMODEL);
    for (int d4 = 0; d4 < 64; ++d4) {
      float4 qv = qrow[d4];
#pragma unroll
      for (int t = 0; t < FB; ++t) {
        float4 xv = *(const float4*)(&xs[t][d4 * 4]);
        accv[t] = fmaf(qv.x, xv.x, accv[t]);
        accv[t] = fmaf(qv.y, xv.y, accv[t]);
        accv[t] = fmaf(qv.z, xv.z, accv[t]);
        accv[t] = fmaf(qv.w, xv.w, accv[t]);
      }
    }
#pragma unroll
    for (int t = 0; t < FB; ++t) sco[t][tid] = accv[t];
    __syncthreads();
    {
      int g = tid >> 4, j = tid & 15;
      float bv = -1e30f; int bs = 256;
#pragma unroll
      for (int k = 0; k < 16; ++k) {
        int s = j + k * 16;
        float v = sco[g][s];
        if (v > bv) { bv = v; bs = s; }
      }
#pragma unroll
      for (int off = 1; off < 16; off <<= 1) {
        float ov = __shfl_xor(bv, off, 64);
        int   os = __shfl_xor(bs, off, 64);
        if (ov > bv || (ov == bv && os < bs)) { bv = ov; bs = os; }
      }
      if (j == 0) {
        int tok = toks[g];
        int olds = (int)idxa[tok];
        if (bs != olds) {
          hard[(size_t)tok * NQQ + olds] = 0.f;
          hard[(size_t)tok * NQQ + bs] = 1.f;
          idxa[tok] = (unsigned char)bs;
        }
      }
    }
    __syncthreads();
  }
}

// reduce+out fused: per (b, slot-group) accumulate x rows by idx into LDS, then
// directly compute out[b, sg*16+ss, :] = S_row . MT — S never touches HBM.
__global__ __launch_bounds__(512) void reduce_kernel(
    const float* __restrict__ x, const unsigned char* __restrict__ idxa,
    const float* __restrict__ MT, float* __restrict__ out) {
  __shared__ unsigned char  idx_l[NN];
  __shared__ unsigned short list_l[NN];
  __shared__ float accs[2][16][DMODEL];
  __shared__ unsigned lcnt;
  const int tid = threadIdx.x;
  const int b  = blockIdx.x >> 4;
  const int sg = blockIdx.x & 15;
  const int h  = tid >> 8;
  const int d  = tid & 255;

  uint4 myidx = ((const uint4*)(idxa + (size_t)b * NN))[tid];
  ((uint4*)idx_l)[tid] = myidx;
  float* af = &accs[0][0][0];
#pragma unroll
  for (int i = 0; i < 16; ++i) af[i * 512 + tid] = 0.f;
  if (tid == 0) lcnt = 0u;
  __syncthreads();

  // phase 1: compaction
  {
    unsigned base = (unsigned)tid * 16u;
    unsigned words[4] = {myidx.x, myidx.y, myidx.z, myidx.w};
#pragma unroll
    for (int wi = 0; wi < 4; ++wi)
#pragma unroll
      for (int j = 0; j < 4; ++j) {
        int s = (words[wi] >> (8 * j)) & 255;
        if ((s >> 4) == sg) {
          unsigned pos = atomicAdd(&lcnt, 1u);
          list_l[pos] = (unsigned short)(base + wi * 4 + j);
        }
      }
  }
  __syncthreads();

  // phase 2: accumulate matching rows
  const int cnt_ = (int)lcnt;
  const float* xb = x + (size_t)b * NN * DMODEL + d;
  float* myacc = &accs[h][0][0] + d;
  int start = (h * cnt_) >> 1;
  int end   = ((h + 1) * cnt_) >> 1;
  int i = start;
  for (; i + 4 <= end; i += 4) {
    int na = list_l[i], nb2 = list_l[i + 1], nc = list_l[i + 2], nd = list_l[i + 3];
    float va = xb[(size_t)na * DMODEL];
    float vb = xb[(size_t)nb2 * DMODEL];
    float vc = xb[(size_t)nc * DMODEL];
    float vd = xb[(size_t)nd * DMODEL];
    myacc[(idx_l[na] & 15) * DMODEL] += va;
    myacc[(idx_l[nb2] & 15) * DMODEL] += vb;
    myacc[(idx_l[nc] & 15) * DMODEL] += vc;
    myacc[(idx_l[nd] & 15) * DMODEL] += vd;
  }
  for (; i < end; ++i) {
    int nn = list_l[i];
    myacc[(idx_l[nn] & 15) * DMODEL] += xb[(size_t)nn * DMODEL];
  }
  __syncthreads();

  // combine halves: accs[0] += accs[1]
#pragma unroll
  for (int ii = 0; ii < 8; ++ii) {
    int u = ii * 512 + tid;
    accs[0][u >> 8][u & 255] += accs[1][u >> 8][u & 255];
  }
  __syncthreads();

  // fused out: rows ss = h*8 .. h*8+7 of this slot-group
  float a[8];
#pragma unroll
  for (int i2 = 0; i2 < 8; ++i2) a[i2] = 0.f;
  for (int dm = 0; dm < DMODEL; ++dm) {
    float m = MT[(size_t)dm * DMODEL + d];
#pragma unroll
    for (int i2 = 0; i2 < 8; ++i2)
      a[i2] = fmaf(accs[0][h * 8 + i2][dm], m, a[i2]);
  }
  float* ob = out + ((size_t)b * NQQ + sg * 16 + h * 8) * DMODEL + d;
#pragma unroll
  for (int i2 = 0; i2 < 8; ++i2) ob[(size_t)i2 * DMODEL] = a[i2];
}

extern "C" void kernel_launch(void* const* d_in, const int* in_sizes, int n_in,
                              void* d_out, int out_size, void* d_ws, size_t ws_size,
                              hipStream_t stream) {
  const float* x   = (const float*)d_in[0];
  const float* q   = (const float*)d_in[1];
  const float* wks = (const float*)d_in[2];
  const float* wvs = (const float*)d_in[3];
  const float* wfc = (const float*)d_in[4];

  float* out  = (float*)d_out;                       // (16,256,256)
  float* hard = out + (size_t)BB * NQQ * DMODEL;     // (16,8192,256)

  float* qk = (float*)d_ws;                          // 256 KB
  float* MT = qk + 65536;                            // 256 KB
  unsigned* cnt  = (unsigned*)(MT + 65536);          // 256 B
  unsigned* listF = cnt + 64;                        // 512 KB
  unsigned short* qhf = (unsigned short*)(listF + CAPF);  // 128 KB
  unsigned char*  idxa = (unsigned char*)(qhf + 65536);   // 128 KB

  (void)hipMemsetAsync(cnt, 0, 256, stream);
  prep_kernel<<<2 * NQQ, 256, 0, stream>>>(q, wks, wvs, wfc, qk, MT, qhf);
  score_kernel<<<dim3(NN / TOK, BB), 256, 0, stream>>>(x, qhf, hard, idxa, cnt, listF);
  fullcheck_kernel<<<1024, 256, 0, stream>>>(x, qk, cnt, listF, hard, idxa);
  reduce_kernel<<<BB * 16, 512, 0, stream>>>(x, idxa, MT, out);
}